// Round 1
// baseline (194.849 us; speedup 1.0000x reference)
//
#include <hip/hip_runtime.h>
#include <stdint.h>

typedef unsigned short ushort_t;
typedef __attribute__((ext_vector_type(8))) short bf16x8;
typedef __attribute__((ext_vector_type(4))) float f32x4;
typedef __attribute__((ext_vector_type(8))) unsigned short u16x8;

#define NROW 4096
#define DDIM 512
#define NTOT 8192

// ---------------- ws layout (bytes) ----------------
// 0        : Wb  bf16[4096*512]   (4 MiB)
// 4 MiB    : Gb  bf16[4096*512]   (4 MiB)
// 8388608  : sqbW float[4096]
// 8404992  : sqbG float[4096]
// 8421376  : u double[4096]       (zeroed each launch)
// 8454144  : v double[4096]       (zeroed)
// 8486912  : s float[512]         (zeroed)
// 8488960  : sc: [0]=sumsq dbl, [1]=P dbl, (float*)(sc+2)=scale (zeroed)
#define WB_OFF   0u
#define GB_OFF   4194304u
#define SQBW_OFF 8388608u
#define SQBG_OFF 8404992u
#define U_OFF    8421376u
#define V_OFF    8454144u
#define S_OFF    8486912u
#define SC_OFF   8488960u

__device__ __forceinline__ void atomAddF64(double* p, double v) {
  __hip_atomic_fetch_add(p, v, __ATOMIC_RELAXED, __HIP_MEMORY_SCOPE_AGENT);
}
__device__ __forceinline__ void atomAddF32(float* p, float v) {
  __hip_atomic_fetch_add(p, v, __ATOMIC_RELAXED, __HIP_MEMORY_SCOPE_AGENT);
}

__device__ __forceinline__ unsigned short f2bf(float f) {
  unsigned int uu = __float_as_uint(f);
  uu = uu + 0x7FFFu + ((uu >> 16) & 1u);  // RNE
  return (unsigned short)(uu >> 16);
}
__device__ __forceinline__ float bf2f(unsigned short h) {
  return __uint_as_float(((unsigned int)h) << 16);
}

__device__ __forceinline__ void gload16(const void* g, void* l) {
  __builtin_amdgcn_global_load_lds(
      (const __attribute__((address_space(1))) unsigned int*)g,
      (__attribute__((address_space(3))) unsigned int*)l, 16, 0, 0);
}

// ---- prep: fp32 -> bf16, per-row sum-of-squares (bf16-consistent) and fp32 sumsq
__global__ __launch_bounds__(64) void prep_rows(
    const float* __restrict__ W, const float* __restrict__ G,
    ushort_t* __restrict__ Wb, ushort_t* __restrict__ Gb,
    float* __restrict__ sqbW, float* __restrict__ sqbG,
    double* __restrict__ sumsq)
{
  const int row = blockIdx.x;   // 0..8191
  const int l = threadIdx.x;    // 0..63, one wave per row
  const float* src; ushort_t* dst; float* sqb; int r;
  if (row < NROW) { src = W + (size_t)row * DDIM; dst = Wb + (size_t)row * DDIM; sqb = sqbW; r = row; }
  else            { src = G + (size_t)(row - NROW) * DDIM; dst = Gb + (size_t)(row - NROW) * DDIM; sqb = sqbG; r = row - NROW; }
  const f32x4 a = *(const f32x4*)(src + l * 8);
  const f32x4 b = *(const f32x4*)(src + l * 8 + 4);
  float s32 = 0.f, sb = 0.f;
  u16x8 h;
  #pragma unroll
  for (int j = 0; j < 4; ++j) {
    float x = a[j]; unsigned short q = f2bf(x); h[j] = q;
    float xb = bf2f(q); s32 += x * x; sb += xb * xb;
  }
  #pragma unroll
  for (int j = 0; j < 4; ++j) {
    float x = b[j]; unsigned short q = f2bf(x); h[4 + j] = q;
    float xb = bf2f(q); s32 += x * x; sb += xb * xb;
  }
  *(u16x8*)(dst + l * 8) = h;
  #pragma unroll
  for (int off = 32; off > 0; off >>= 1) { s32 += __shfl_down(s32, off); sb += __shfl_down(sb, off); }
  if (l == 0) { sqb[r] = sb; atomAddF64(sumsq, (double)s32); }
}

// ---- column sums of concat(W,G) (fp32) for closed-form sum(d2)
__global__ __launch_bounds__(256) void colsum(
    const float* __restrict__ W, const float* __restrict__ G, float* __restrict__ s)
{
  const int t = blockIdx.x * 256 + threadIdx.x;  // 0..16383
  const int c = t & 511;
  const int chunk = t >> 9;                      // 0..31 chunks of 256 rows
  const float* src = (chunk < 16) ? (W + (size_t)chunk * 256 * DDIM)
                                  : (G + (size_t)(chunk - 16) * 256 * DDIM);
  float acc = 0.f;
  for (int r = 0; r < 256; ++r) acc += src[(size_t)r * DDIM + c];
  atomAddF32(&s[c], acc);
}

// ---- bandwidth scalar:  bw = (2N*sumsq - 2*||colsum||^2)/(N^2-N)/4 ; scale = log2e/(16*bw)
__global__ __launch_bounds__(256) void bwk(
    const float* __restrict__ s, const double* __restrict__ sumsq, float* __restrict__ scale)
{
  __shared__ double red[256];
  const int t = threadIdx.x;
  double s2 = 0.0;
  for (int c = t; c < 512; c += 256) { double x = (double)s[c]; s2 += x * x; }
  red[t] = s2; __syncthreads();
  for (int k = 128; k > 0; k >>= 1) { if (t < k) red[t] += red[t + k]; __syncthreads(); }
  if (t == 0) {
    double sum_d2 = 2.0 * 8192.0 * sumsq[0] - 2.0 * red[0];
    double bw = sum_d2 / (8192.0 * 8191.0) / 4.0;
    scale[0] = (float)(1.4426950408889634 / (bw * 16.0));
  }
}

// ---- Gram K-loop: acc[m][n] += rows(i0..i0+127) . rows(j0..j0+127) over D=512
__device__ __forceinline__ void gram_accum(
    const ushort_t* __restrict__ src, int i0, int j0,
    int tid, int lane, int wr, int wc,
    ushort_t* __restrict__ At, ushort_t* __restrict__ Bt,
    f32x4 acc[4][4])
{
  #pragma unroll
  for (int m = 0; m < 4; ++m)
    #pragma unroll
    for (int n = 0; n < 4; ++n) acc[m][n] = (f32x4)0.0f;

  const int g = lane >> 4;
  const int lr = lane & 15;

  for (int st = 0; st < 8; ++st) {
    // stage 128x64 bf16 tiles A(i-rows) and B(j-rows); linear LDS dest,
    // inverse-XOR-swizzled global source (rule #21 / T2)
    #pragma unroll
    for (int q = 0; q < 4; ++q) {
      const int slot = q * 256 + tid;   // 0..1023, 16B each
      const int row = slot >> 3;
      const int sc = slot & 7;
      const int c = sc ^ (row & 7);
      const char* gA = (const char*)src + ((size_t)(i0 + row) * DDIM + st * 64) * 2 + c * 16;
      gload16(gA, (char*)At + slot * 16);
      const char* gB = (const char*)src + ((size_t)(j0 + row) * DDIM + st * 64) * 2 + c * 16;
      gload16(gB, (char*)Bt + slot * 16);
    }
    __syncthreads();
    #pragma unroll
    for (int kk = 0; kk < 2; ++kk) {
      bf16x8 a[4], b[4];
      #pragma unroll
      for (int m = 0; m < 4; ++m) {
        const int row = wr * 64 + m * 16 + lr;
        const int c = kk * 4 + g;
        a[m] = *(const bf16x8*)((const char*)At + row * 128 + ((c ^ (row & 7)) * 16));
      }
      #pragma unroll
      for (int n = 0; n < 4; ++n) {
        const int row = wc * 64 + n * 16 + lr;
        const int c = kk * 4 + g;
        b[n] = *(const bf16x8*)((const char*)Bt + row * 128 + ((c ^ (row & 7)) * 16));
      }
      #pragma unroll
      for (int m = 0; m < 4; ++m)
        #pragma unroll
        for (int n = 0; n < 4; ++n)
          acc[m][n] = __builtin_amdgcn_mfma_f32_16x16x32_bf16(a[m], b[n], acc[m][n], 0, 0, 0);
    }
    __syncthreads();
  }
}

// ---- main fused kernel: both Grams for tile (i0,j0), kernel values, reductions
__global__ __launch_bounds__(256, 2) void gram_kernel(
    const ushort_t* __restrict__ Wb, const ushort_t* __restrict__ Gb,
    const float* __restrict__ sqbW, const float* __restrict__ sqbG,
    const float* __restrict__ scale,
    double* __restrict__ u, double* __restrict__ v, double* __restrict__ P)
{
  __shared__ ushort_t At[128 * 64];
  __shared__ ushort_t Bt[128 * 64];
  __shared__ double pred[4];

  const int tid = threadIdx.x;
  const int lane = tid & 63;
  const int wid = tid >> 6;
  const int wr = wid >> 1;
  const int wc = wid & 1;
  const int i0 = blockIdx.y * 128;
  const int j0 = blockIdx.x * 128;
  const int g = lane >> 4;
  const int lr = lane & 15;

  f32x4 accW[4][4], accG[4][4];
  gram_accum(Wb, i0, j0, tid, lane, wr, wc, At, Bt, accW);
  gram_accum(Gb, i0, j0, tid, lane, wr, wc, At, Bt, accG);

  const float s4 = scale[0];

  // preload row/col sq values (C layout: col=lane&15, row=(lane>>4)*4+e)
  float riW[16], riG[16], rjW[4], rjG[4];
  #pragma unroll
  for (int m = 0; m < 4; ++m)
    #pragma unroll
    for (int e = 0; e < 4; ++e) {
      const int i = i0 + wr * 64 + m * 16 + g * 4 + e;
      riW[m * 4 + e] = sqbW[i];
      riG[m * 4 + e] = sqbG[i];
    }
  #pragma unroll
  for (int n = 0; n < 4; ++n) {
    const int j = j0 + wc * 64 + n * 16 + lr;
    rjW[n] = sqbW[j];
    rjG[n] = sqbG[j];
  }

  double p_loc = 0.0;
  float rsW[4][4], rsG[4][4];
  #pragma unroll
  for (int m = 0; m < 4; ++m)
    #pragma unroll
    for (int e = 0; e < 4; ++e) { rsW[m][e] = 0.f; rsG[m][e] = 0.f; }

  #pragma unroll
  for (int m = 0; m < 4; ++m) {
    #pragma unroll
    for (int n = 0; n < 4; ++n) {
      #pragma unroll
      for (int e = 0; e < 4; ++e) {
        // K = y + y^2 + y^4 + y^8 + y^16 with y = exp(-d2/(16*bw)): 1 transcendental
        float d2w = fmaxf(riW[m * 4 + e] + rjW[n] - 2.f * accW[m][n][e], 0.f);
        float yw = exp2f(-d2w * s4);
        float yw2 = yw * yw, yw4 = yw2 * yw2, yw8 = yw4 * yw4, yw16 = yw8 * yw8;
        float kw = yw + yw2 + yw4 + yw8 + yw16;
        float d2g = fmaxf(riG[m * 4 + e] + rjG[n] - 2.f * accG[m][n][e], 0.f);
        float yg = exp2f(-d2g * s4);
        float yg2 = yg * yg, yg4 = yg2 * yg2, yg8 = yg4 * yg4, yg16 = yg8 * yg8;
        float kg = yg + yg2 + yg4 + yg8 + yg16;
        p_loc += (double)(kw * kg);
        rsW[m][e] += kw;
        rsG[m][e] += kg;
      }
    }
  }

  // row sums: butterfly over the 16 column-lanes, one f64 atomic per row
  #pragma unroll
  for (int m = 0; m < 4; ++m)
    #pragma unroll
    for (int e = 0; e < 4; ++e) {
      float x = rsW[m][e];
      float y = rsG[m][e];
      x += __shfl_xor(x, 1); x += __shfl_xor(x, 2); x += __shfl_xor(x, 4); x += __shfl_xor(x, 8);
      y += __shfl_xor(y, 1); y += __shfl_xor(y, 2); y += __shfl_xor(y, 4); y += __shfl_xor(y, 8);
      if (lr == 0) {
        const int i = i0 + wr * 64 + m * 16 + g * 4 + e;
        atomAddF64(&u[i], (double)x);
        atomAddF64(&v[i], (double)y);
      }
    }

  // P: wave butterfly then one atomic per block
  #pragma unroll
  for (int off = 32; off > 0; off >>= 1) p_loc += __shfl_xor(p_loc, off);
  if (lane == 0) pred[wid] = p_loc;
  __syncthreads();
  if (tid == 0) atomAddF64(P, pred[0] + pred[1] + pred[2] + pred[3]);
}

// ---- finalize: loss = -(P - (2/n) u.v + Su*Sv/n^2) / (n-1)^2
__global__ __launch_bounds__(256) void finalize(
    const double* __restrict__ u, const double* __restrict__ v,
    const double* __restrict__ P, float* __restrict__ out)
{
  __shared__ double r0[256], r1[256], r2[256];
  const int t = threadIdx.x;
  double uv = 0.0, su = 0.0, sv = 0.0;
  for (int i = t; i < NROW; i += 256) { double a = u[i], b = v[i]; uv += a * b; su += a; sv += b; }
  r0[t] = uv; r1[t] = su; r2[t] = sv; __syncthreads();
  for (int k = 128; k > 0; k >>= 1) {
    if (t < k) { r0[t] += r0[t + k]; r1[t] += r1[t + k]; r2[t] += r2[t + k]; }
    __syncthreads();
  }
  if (t == 0) {
    const double n = 4096.0;
    double hsic = P[0] - (2.0 / n) * r0[0] + (r1[0] * r2[0]) / (n * n);
    out[0] = (float)(-hsic / ((n - 1.0) * (n - 1.0)));
  }
}

extern "C" void kernel_launch(void* const* d_in, const int* in_sizes, int n_in,
                              void* d_out, int out_size, void* d_ws, size_t ws_size,
                              hipStream_t stream) {
  const float* W = (const float*)d_in[0];
  const float* G = (const float*)d_in[1];
  char* ws = (char*)d_ws;
  ushort_t* Wb = (ushort_t*)(ws + WB_OFF);
  ushort_t* Gb = (ushort_t*)(ws + GB_OFF);
  float* sqbW = (float*)(ws + SQBW_OFF);
  float* sqbG = (float*)(ws + SQBG_OFF);
  double* u = (double*)(ws + U_OFF);
  double* v = (double*)(ws + V_OFF);
  float* s = (float*)(ws + S_OFF);
  double* sc = (double*)(ws + SC_OFF);   // [0]=sumsq, [1]=P, (float*)(sc+2)=scale

  // zero accumulators (u, v, s, scalars) — fresh every launch (graph-replay safe)
  hipMemsetAsync(ws + U_OFF, 0, (SC_OFF + 64) - U_OFF, stream);

  prep_rows<<<NTOT, 64, 0, stream>>>(W, G, Wb, Gb, sqbW, sqbG, &sc[0]);
  colsum<<<64, 256, 0, stream>>>(W, G, s);
  bwk<<<1, 256, 0, stream>>>(s, &sc[0], (float*)(sc + 2));
  dim3 grid(32, 32);
  gram_kernel<<<grid, 256, 0, stream>>>(Wb, Gb, sqbW, sqbG, (const float*)(sc + 2), u, v, &sc[1]);
  finalize<<<1, 256, 0, stream>>>(u, v, &sc[1], (float*)d_out);
}

// Round 2
// 90.790 us; speedup vs baseline: 2.1462x; 2.1462x over previous
//
#include <hip/hip_runtime.h>
#include <stdint.h>

typedef unsigned short ushort_t;
typedef __attribute__((ext_vector_type(8))) short bf16x8;
typedef __attribute__((ext_vector_type(4))) float f32x4;
typedef __attribute__((ext_vector_type(8))) unsigned short u16x8;

#define NROW 4096
#define DDIM 512
#define NTOT 8192

// ---------------- ws layout (bytes) ----------------
#define WB_OFF   0u          // bf16[8192*512] region: Wb 4 MiB
#define GB_OFF   4194304u    // Gb 4 MiB
#define SQBW_OFF 8388608u    // float[4096]
#define SQBG_OFF 8404992u    // float[4096]
#define U_OFF    8421376u    // double[4096]  (zeroed)
#define V_OFF    8454144u    // double[4096]  (zeroed)
#define S_OFF    8486912u    // float[512]    (zeroed)
#define SC_OFF   8488960u    // sc[0]=unused, sc[1]=P dbl, (float*)(sc+2)=scale (zeroed)
#define SSP_OFF  8489088u    // double[256] sumsq partials (zeroed)
#define ZERO_END (SSP_OFF + 2048u)

__device__ __forceinline__ void atomAddF64(double* p, double v) {
  __hip_atomic_fetch_add(p, v, __ATOMIC_RELAXED, __HIP_MEMORY_SCOPE_AGENT);
}
__device__ __forceinline__ void atomAddF32(float* p, float v) {
  __hip_atomic_fetch_add(p, v, __ATOMIC_RELAXED, __HIP_MEMORY_SCOPE_AGENT);
}

__device__ __forceinline__ unsigned short f2bf(float f) {
  unsigned int uu = __float_as_uint(f);
  uu = uu + 0x7FFFu + ((uu >> 16) & 1u);  // RNE
  return (unsigned short)(uu >> 16);
}
__device__ __forceinline__ float bf2f(unsigned short h) {
  return __uint_as_float(((unsigned int)h) << 16);
}

__device__ __forceinline__ void gload16(const void* g, void* l) {
  __builtin_amdgcn_global_load_lds(
      (const __attribute__((address_space(1))) unsigned int*)g,
      (__attribute__((address_space(3))) unsigned int*)l, 16, 0, 0);
}

// ---- prep: fp32 -> bf16, per-row bf16-consistent sumsq; fp32 sumsq -> 256 partial slots
__global__ __launch_bounds__(256) void prep_rows(
    const float* __restrict__ W, const float* __restrict__ G,
    ushort_t* __restrict__ Wb, ushort_t* __restrict__ Gb,
    float* __restrict__ sqbW, float* __restrict__ sqbG,
    double* __restrict__ ssp)
{
  const int row = blockIdx.x * 4 + (threadIdx.x >> 6);  // 0..8191
  const int l = threadIdx.x & 63;
  const float* src; ushort_t* dst; float* sqb; int r;
  if (row < NROW) { src = W + (size_t)row * DDIM; dst = Wb + (size_t)row * DDIM; sqb = sqbW; r = row; }
  else            { src = G + (size_t)(row - NROW) * DDIM; dst = Gb + (size_t)(row - NROW) * DDIM; sqb = sqbG; r = row - NROW; }
  const f32x4 a = *(const f32x4*)(src + l * 8);
  const f32x4 b = *(const f32x4*)(src + l * 8 + 4);
  float s32 = 0.f, sb = 0.f;
  u16x8 h;
  #pragma unroll
  for (int j = 0; j < 4; ++j) {
    float x = a[j]; unsigned short q = f2bf(x); h[j] = q;
    float xb = bf2f(q); s32 += x * x; sb += xb * xb;
  }
  #pragma unroll
  for (int j = 0; j < 4; ++j) {
    float x = b[j]; unsigned short q = f2bf(x); h[4 + j] = q;
    float xb = bf2f(q); s32 += x * x; sb += xb * xb;
  }
  *(u16x8*)(dst + l * 8) = h;
  #pragma unroll
  for (int off = 32; off > 0; off >>= 1) { s32 += __shfl_down(s32, off); sb += __shfl_down(sb, off); }
  if (l == 0) { sqb[r] = sb; atomAddF64(&ssp[blockIdx.x & 255], (double)s32); }
}

// ---- column sums of concat(W,G) (fp32)
__global__ __launch_bounds__(256) void colsum(
    const float* __restrict__ W, const float* __restrict__ G, float* __restrict__ s)
{
  const int t = blockIdx.x * 256 + threadIdx.x;  // 0..65535
  const int c = t & 511;
  const int chunk = t >> 9;                      // 0..127 chunks of 64 rows
  const float* src = (chunk < 64) ? (W + (size_t)chunk * 64 * DDIM)
                                  : (G + (size_t)(chunk - 64) * 64 * DDIM);
  float acc = 0.f;
  for (int r = 0; r < 64; ++r) acc += src[(size_t)r * DDIM + c];
  atomAddF32(&s[c], acc);
}

// ---- bandwidth scalar
__global__ __launch_bounds__(256) void bwk(
    const float* __restrict__ s, const double* __restrict__ ssp, float* __restrict__ scale)
{
  __shared__ double red[256], red2[256];
  const int t = threadIdx.x;
  double s2 = 0.0;
  for (int c = t; c < 512; c += 256) { double x = (double)s[c]; s2 += x * x; }
  red[t] = s2;
  red2[t] = ssp[t];
  __syncthreads();
  for (int k = 128; k > 0; k >>= 1) {
    if (t < k) { red[t] += red[t + k]; red2[t] += red2[t + k]; }
    __syncthreads();
  }
  if (t == 0) {
    double sum_d2 = 2.0 * 8192.0 * red2[0] - 2.0 * red[0];
    double bw = sum_d2 / (8192.0 * 8191.0) / 4.0;
    scale[0] = (float)(1.4426950408889634 / (bw * 16.0));
  }
}

// ---- Gram K-loop: acc[m][n] += rows(i0..i0+127) . rows(j0..j0+127) over D=512
__device__ __forceinline__ void gram_accum(
    const ushort_t* __restrict__ src, int i0, int j0,
    int tid, int lane, int wr, int wc,
    ushort_t* __restrict__ At, ushort_t* __restrict__ Bt,
    f32x4 acc[4][4])
{
  #pragma unroll
  for (int m = 0; m < 4; ++m)
    #pragma unroll
    for (int n = 0; n < 4; ++n) acc[m][n] = (f32x4)0.0f;

  const int g = lane >> 4;
  const int lr = lane & 15;

  for (int st = 0; st < 8; ++st) {
    #pragma unroll
    for (int q = 0; q < 4; ++q) {
      const int slot = q * 256 + tid;   // 0..1023, 16B each
      const int row = slot >> 3;
      const int sc = slot & 7;
      const int c = sc ^ (row & 7);
      const char* gA = (const char*)src + ((size_t)(i0 + row) * DDIM + st * 64) * 2 + c * 16;
      gload16(gA, (char*)At + slot * 16);
      const char* gB = (const char*)src + ((size_t)(j0 + row) * DDIM + st * 64) * 2 + c * 16;
      gload16(gB, (char*)Bt + slot * 16);
    }
    __syncthreads();
    #pragma unroll
    for (int kk = 0; kk < 2; ++kk) {
      bf16x8 a[4], b[4];
      #pragma unroll
      for (int m = 0; m < 4; ++m) {
        const int row = wr * 64 + m * 16 + lr;
        const int c = kk * 4 + g;
        a[m] = *(const bf16x8*)((const char*)At + row * 128 + ((c ^ (row & 7)) * 16));
      }
      #pragma unroll
      for (int n = 0; n < 4; ++n) {
        const int row = wc * 64 + n * 16 + lr;
        const int c = kk * 4 + g;
        b[n] = *(const bf16x8*)((const char*)Bt + row * 128 + ((c ^ (row & 7)) * 16));
      }
      #pragma unroll
      for (int m = 0; m < 4; ++m)
        #pragma unroll
        for (int n = 0; n < 4; ++n)
          acc[m][n] = __builtin_amdgcn_mfma_f32_16x16x32_bf16(a[m], b[n], acc[m][n], 0, 0, 0);
    }
    __syncthreads();
  }
}

// ---- main fused kernel: upper-triangular tiles only (symmetry), both Grams, reductions
__global__ __launch_bounds__(256, 2) void gram_kernel(
    const ushort_t* __restrict__ Wb, const ushort_t* __restrict__ Gb,
    const float* __restrict__ sqbW, const float* __restrict__ sqbG,
    const float* __restrict__ scale,
    double* __restrict__ u, double* __restrict__ v, double* __restrict__ P)
{
  __shared__ ushort_t At[128 * 64];
  __shared__ ushort_t Bt[128 * 64];
  __shared__ double pred[4];

  // decode upper-triangular tile index: 0 <= bi <= bj < 32
  int t = blockIdx.x;
  int bi = 0;
  while (t >= 32 - bi) { t -= 32 - bi; ++bi; }
  const int bj = bi + t;
  const bool offdiag = (bi != bj);

  const int tid = threadIdx.x;
  const int lane = tid & 63;
  const int wid = tid >> 6;
  const int wr = wid >> 1;
  const int wc = wid & 1;
  const int i0 = bi * 128;
  const int j0 = bj * 128;
  const int g = lane >> 4;
  const int lr = lane & 15;

  f32x4 accW[4][4], accG[4][4];
  gram_accum(Wb, i0, j0, tid, lane, wr, wc, At, Bt, accW);
  gram_accum(Gb, i0, j0, tid, lane, wr, wc, At, Bt, accG);

  const float s4 = scale[0];

  float riW[16], riG[16], rjW[4], rjG[4];
  #pragma unroll
  for (int m = 0; m < 4; ++m)
    #pragma unroll
    for (int e = 0; e < 4; ++e) {
      const int i = i0 + wr * 64 + m * 16 + g * 4 + e;
      riW[m * 4 + e] = sqbW[i];
      riG[m * 4 + e] = sqbG[i];
    }
  #pragma unroll
  for (int n = 0; n < 4; ++n) {
    const int j = j0 + wc * 64 + n * 16 + lr;
    rjW[n] = sqbW[j];
    rjG[n] = sqbG[j];
  }

  double p_loc = 0.0;
  float rsW[4][4], rsG[4][4], csW[4], csG[4];
  #pragma unroll
  for (int m = 0; m < 4; ++m)
    #pragma unroll
    for (int e = 0; e < 4; ++e) { rsW[m][e] = 0.f; rsG[m][e] = 0.f; }
  #pragma unroll
  for (int n = 0; n < 4; ++n) { csW[n] = 0.f; csG[n] = 0.f; }

  #pragma unroll
  for (int m = 0; m < 4; ++m) {
    #pragma unroll
    for (int n = 0; n < 4; ++n) {
      #pragma unroll
      for (int e = 0; e < 4; ++e) {
        // K = y + y^2 + y^4 + y^8 + y^16, y = exp(-d2/(16*bw)) : one transcendental
        float d2w = fmaxf(riW[m * 4 + e] + rjW[n] - 2.f * accW[m][n][e], 0.f);
        float yw = exp2f(-d2w * s4);
        float yw2 = yw * yw, yw4 = yw2 * yw2, yw8 = yw4 * yw4, yw16 = yw8 * yw8;
        float kw = yw + yw2 + yw4 + yw8 + yw16;
        float d2g = fmaxf(riG[m * 4 + e] + rjG[n] - 2.f * accG[m][n][e], 0.f);
        float yg = exp2f(-d2g * s4);
        float yg2 = yg * yg, yg4 = yg2 * yg2, yg8 = yg4 * yg4, yg16 = yg8 * yg8;
        float kg = yg + yg2 + yg4 + yg8 + yg16;
        p_loc += (double)(kw * kg);
        rsW[m][e] += kw;
        rsG[m][e] += kg;
        csW[n] += kw;
        csG[n] += kg;
      }
    }
  }

  // row sums (over the tile's j-columns): butterfly across the 16 column-lanes
  #pragma unroll
  for (int m = 0; m < 4; ++m)
    #pragma unroll
    for (int e = 0; e < 4; ++e) {
      float x = rsW[m][e];
      float y = rsG[m][e];
      x += __shfl_xor(x, 1); x += __shfl_xor(x, 2); x += __shfl_xor(x, 4); x += __shfl_xor(x, 8);
      y += __shfl_xor(y, 1); y += __shfl_xor(y, 2); y += __shfl_xor(y, 4); y += __shfl_xor(y, 8);
      if (lr == 0) {
        const int i = i0 + wr * 64 + m * 16 + g * 4 + e;
        atomAddF64(&u[i], (double)x);
        atomAddF64(&v[i], (double)y);
      }
    }

  // off-diagonal: column sums feed the transposed half (K symmetric)
  if (offdiag) {
    #pragma unroll
    for (int n = 0; n < 4; ++n) {
      float x = csW[n];
      float y = csG[n];
      x += __shfl_xor(x, 16); x += __shfl_xor(x, 32);
      y += __shfl_xor(y, 16); y += __shfl_xor(y, 32);
      if (g == 0) {
        const int j = j0 + wc * 64 + n * 16 + lr;
        atomAddF64(&u[j], (double)x);
        atomAddF64(&v[j], (double)y);
      }
    }
  }

  // P: wave butterfly then one atomic per block (off-diag counts twice)
  #pragma unroll
  for (int off = 32; off > 0; off >>= 1) p_loc += __shfl_xor(p_loc, off);
  if (lane == 0) pred[wid] = p_loc;
  __syncthreads();
  if (tid == 0) {
    double ps = pred[0] + pred[1] + pred[2] + pred[3];
    atomAddF64(P, offdiag ? 2.0 * ps : ps);
  }
}

// ---- finalize: loss = -(P - (2/n) u.v + Su*Sv/n^2) / (n-1)^2
__global__ __launch_bounds__(256) void finalize(
    const double* __restrict__ u, const double* __restrict__ v,
    const double* __restrict__ P, float* __restrict__ out)
{
  __shared__ double r0[256], r1[256], r2[256];
  const int t = threadIdx.x;
  double uv = 0.0, su = 0.0, sv = 0.0;
  for (int i = t; i < NROW; i += 256) { double a = u[i], b = v[i]; uv += a * b; su += a; sv += b; }
  r0[t] = uv; r1[t] = su; r2[t] = sv; __syncthreads();
  for (int k = 128; k > 0; k >>= 1) {
    if (t < k) { r0[t] += r0[t + k]; r1[t] += r1[t + k]; r2[t] += r2[t + k]; }
    __syncthreads();
  }
  if (t == 0) {
    const double n = 4096.0;
    double hsic = P[0] - (2.0 / n) * r0[0] + (r1[0] * r2[0]) / (n * n);
    out[0] = (float)(-hsic / ((n - 1.0) * (n - 1.0)));
  }
}

extern "C" void kernel_launch(void* const* d_in, const int* in_sizes, int n_in,
                              void* d_out, int out_size, void* d_ws, size_t ws_size,
                              hipStream_t stream) {
  const float* W = (const float*)d_in[0];
  const float* G = (const float*)d_in[1];
  char* ws = (char*)d_ws;
  ushort_t* Wb = (ushort_t*)(ws + WB_OFF);
  ushort_t* Gb = (ushort_t*)(ws + GB_OFF);
  float* sqbW = (float*)(ws + SQBW_OFF);
  float* sqbG = (float*)(ws + SQBG_OFF);
  double* u = (double*)(ws + U_OFF);
  double* v = (double*)(ws + V_OFF);
  float* s = (float*)(ws + S_OFF);
  double* sc = (double*)(ws + SC_OFF);   // sc[1]=P, (float*)(sc+2)=scale
  double* ssp = (double*)(ws + SSP_OFF); // 256 sumsq partials

  // zero accumulators (u, v, s, sc, ssp) — fresh every launch (graph-replay safe)
  hipMemsetAsync(ws + U_OFF, 0, ZERO_END - U_OFF, stream);

  prep_rows<<<2048, 256, 0, stream>>>(W, G, Wb, Gb, sqbW, sqbG, ssp);
  colsum<<<256, 256, 0, stream>>>(W, G, s);
  bwk<<<1, 256, 0, stream>>>(s, ssp, (float*)(sc + 2));
  gram_kernel<<<528, 256, 0, stream>>>(Wb, Gb, sqbW, sqbG, (const float*)(sc + 2), u, v, &sc[1]);
  finalize<<<1, 256, 0, stream>>>(u, v, &sc[1], (float*)d_out);
}